// Round 7
// baseline (494.441 us; speedup 1.0000x reference)
//
#include <hip/hip_runtime.h>
#include <hip/hip_bf16.h>

constexpr int kHD  = 10;   // hidden dim
constexpr int kP   = 6;    // parts
constexpr int kNE  = 5;    // edges
constexpr int kH   = 128;  // part-map H=W
constexpr int kHin = 64;   // coarse-map H=W
constexpr int kXhRows = 6; // staged source rows per block (span<=5 +1)
constexpr int kSegXh  = 2 * kHD * kXhRows;       // 120
constexpr int kSegTot = kSegXh + 4 * kHD;        // +40 xf segs = 160

__device__ __forceinline__ float sigm(float v) {
    return 1.0f / (1.0f + __expf(-v));
}

__device__ __forceinline__ void load_xp(const float* __restrict__ base, int offpix,
                                        float (&x)[kP][kHD]) {
    #pragma unroll
    for (int p = 0; p < kP; ++p)
        #pragma unroll
        for (int c = 0; c < kHD; ++c)
            x[p][c] = base[(size_t)(p * kHD + c) * (kH * kH) + offpix];
}

__device__ __forceinline__ void compute_store(
    int j, int n, int yc, int xc, int ry0, int x0, float fx,
    const float* __restrict__ lds,
    const float (&xpv)[kP][kHD],
    const float* __restrict__ Wf,  const float* __restrict__ bfb,
    const float* __restrict__ Wh,  const float* __restrict__ bhb,
    const float* __restrict__ Watt, const float* __restrict__ batt,
    const float* __restrict__ Wdp, const float* __restrict__ Wup,
    float* __restrict__ out_xp, float* __restrict__ out_att)
{
    // bilinear row coords for this pixel
    const float py = (float)yc * (63.0f / 127.0f);
    int y0 = (int)py; y0 = y0 > (kHin - 2) ? (kHin - 2) : y0;
    const float fy = py - (float)y0;
    const int d0 = y0 - ry0;                  // 0..4 within staged rows

    const float w00 = (1.0f - fy) * (1.0f - fx);
    const float w01 = (1.0f - fy) * fx;
    const float w10 = fy * (1.0f - fx);
    const float w11 = fy * fx;

    float xh0v[kHD], xh1v[kHD], xfv[kHD];
    #pragma unroll
    for (int c = 0; c < kHD; ++c) {
        const float* r0 = &lds[((0 * kHD + c) * kXhRows + d0) * kHin];
        xh0v[c] = r0[x0] * w00 + r0[x0 + 1] * w01 +
                  r0[kHin + x0] * w10 + r0[kHin + x0 + 1] * w11;
        const float* r1 = &lds[((1 * kHD + c) * kXhRows + d0) * kHin];
        xh1v[c] = r1[x0] * w00 + r1[x0 + 1] * w01 +
                  r1[kHin + x0] * w10 + r1[kHin + x0 + 1] * w11;
    }
    const int sx = xc >> 1;
    #pragma unroll
    for (int c = 0; c < kHD; ++c)
        xfv[c] = lds[(kSegXh + j * kHD + c) * kHin + sx];

    // ---- attentions ----
    float attf[kP], atth[kP], dpa[kP];
    #pragma unroll
    for (int p = 0; p < kP; ++p) {
        float af = bfb[p];
        float ah = bhb[p];
        float ad = batt[p];
        #pragma unroll
        for (int c = 0; c < kHD; ++c) {
            const float xhc = (p < 4) ? xh0v[c] : xh1v[c];
            af += xfv[c]    * Wf[p * 2 * kHD + c];
            af += xpv[p][c] * Wf[p * 2 * kHD + kHD + c];
            ah += xhc       * Wh[p * 2 * kHD + c];
            ah += xpv[p][c] * Wh[p * 2 * kHD + kHD + c];
            ad += xpv[p][c] * Watt[p * kHD + c];
        }
        attf[p] = sigm(af);
        atth[p] = sigm(ah);
        dpa[p]  = sigm(ad);
    }

    const size_t pixoff = (size_t)yc * kH + xc;
    #pragma unroll
    for (int p = 0; p < kP; ++p) {
        const float ap = (attf[p] + atth[p] + dpa[p]) * (1.0f / 3.0f);
        out_att[(size_t)(n * kP + p) * (kH * kH) + pixoff] = ap;
    }

    // ---- edge messages -> xpp ----
    float xpp[kP][kHD];
    #pragma unroll
    for (int p = 0; p < kP; ++p)
        #pragma unroll
        for (int c = 0; c < kHD; ++c) xpp[p][c] = 0.0f;

    constexpr int EA[kNE] = {0, 1, 2, 1, 4};
    constexpr int EB[kNE] = {1, 2, 3, 4, 5};
    #pragma unroll
    for (int e = 0; e < kNE; ++e) {
        const int a = EA[e], b = EB[e];
        const float sa = 2.0f - dpa[a];
        const float sb = 2.0f - dpa[b];
        #pragma unroll
        for (int d = 0; d < kHD; ++d) {
            const float* w = Wdp + (size_t)(e * kHD + d) * (2 * kHD);
            float t = 0.0f;
            #pragma unroll
            for (int c = 0; c < kHD; ++c) t += xpv[a][c] * w[c];
            #pragma unroll
            for (int c = 0; c < kHD; ++c) t += xpv[b][c] * w[kHD + c];
            t = fmaxf(t, 0.0f);
            xpp[b][d] += t * sa;
            xpp[a][d] += t * sb;
        }
    }

    // ---- update + stores ----
    #pragma unroll
    for (int p = 0; p < kP; ++p) {
        #pragma unroll
        for (int d = 0; d < kHD; ++d) {
            const float* w = Wup + (size_t)(p * kHD + d) * (4 * kHD);
            float a1 = 0.0f, a2 = 0.0f, a3 = 0.0f, a4 = 0.0f;
            #pragma unroll
            for (int c = 0; c < kHD; ++c) {
                const float xhc = (p < 4) ? xh0v[c] : xh1v[c];
                a1 += xpv[p][c] * w[c];
                a2 += xfv[c]    * w[kHD + c];
                a3 += xhc       * w[2 * kHD + c];
                a4 += xpp[p][c] * w[3 * kHD + c];
            }
            float upd = a1 + attf[p] * a2 + atth[p] * a3 + a4;
            upd = fmaxf(upd, 0.0f);
            float o = xpv[p][d] + upd;
            o = fmaxf(o, 0.0f);
            out_xp[(size_t)(n * kP * kHD + p * kHD + d) * (kH * kH) + pixoff] = o;
        }
    }
}

// Block = 256 threads = 8 rows x 128 cols of one image; 4 pixels/thread,
// ping-pong xp prefetch hides HBM latency under previous pixel's compute.
// grid = 512 blocks = 2 blocks/CU -> entire kernel resident in one generation.
__global__ __launch_bounds__(256, 2)
void Part_Graph_51539607552364_kernel(
    const float* __restrict__ xf,  const float* __restrict__ xh0,
    const float* __restrict__ xh1, const float* __restrict__ xp,
    const float* __restrict__ Wf,  const float* __restrict__ bfb,
    const float* __restrict__ Wh,  const float* __restrict__ bhb,
    const float* __restrict__ Watt, const float* __restrict__ batt,
    const float* __restrict__ Wdp, const float* __restrict__ Wup,
    float* __restrict__ out_xp,
    float* __restrict__ out_att)
{
    __shared__ float lds[kSegTot * kHin];   // 160*64*4 = 40960 B

    const int bid = blockIdx.x;
    const int n   = bid >> 4;               // 16 blocks per image
    const int yA  = (bid & 15) << 3;        // first of 8 output rows
    const int ry0 = (int)((float)yA * (63.0f / 127.0f));  // base xh source row
    const int syb = yA >> 1;                // base xf source row

    // ---- cooperative staging: 160 segments of 64 floats ----
    {
        const int wv = threadIdx.x >> 6;
        const int ln = threadIdx.x & 63;
        for (int s = wv; s < kSegTot; s += 4) {
            const float* src;
            if (s < kSegXh) {
                const int mc = s / kXhRows, r = s - mc * kXhRows;
                const int map = mc / kHD, ch = mc - map * kHD;
                int row = ry0 + r; row = row > (kHin - 1) ? (kHin - 1) : row;
                src = (map ? xh1 : xh0) + ((size_t)(n * kHD + ch) * kHin + row) * kHin;
            } else {
                const int t = s - kSegXh;
                const int jr = t / kHD, ch = t - jr * kHD;
                src = xf + ((size_t)(n * kHD + ch) * kHin + (syb + jr)) * kHin;
            }
            lds[s * kHin + ln] = src[ln];
        }
    }
    __syncthreads();

    const int ly = threadIdx.x >> 7;        // 0/1: row within each row-pair
    const int xc = threadIdx.x & (kH - 1);

    const float pxf = (float)xc * (63.0f / 127.0f);
    int x0 = (int)pxf; x0 = x0 > (kHin - 2) ? (kHin - 2) : x0;
    const float fx = pxf - (float)x0;

    const float* xpb = xp + (size_t)n * kP * kHD * kH * kH;
    const int off0 = (yA + ly) * kH + xc;

    float A[kP][kHD], B[kP][kHD];
    load_xp(xpb, off0,          A);   // pixel j=0
    load_xp(xpb, off0 + 2 * kH, B);   // pixel j=1
    compute_store(0, n, yA + 0 + ly, xc, ry0, x0, fx, lds, A,
                  Wf, bfb, Wh, bhb, Watt, batt, Wdp, Wup, out_xp, out_att);
    load_xp(xpb, off0 + 4 * kH, A);   // pixel j=2
    compute_store(1, n, yA + 2 + ly, xc, ry0, x0, fx, lds, B,
                  Wf, bfb, Wh, bhb, Watt, batt, Wdp, Wup, out_xp, out_att);
    load_xp(xpb, off0 + 6 * kH, B);   // pixel j=3
    compute_store(2, n, yA + 4 + ly, xc, ry0, x0, fx, lds, A,
                  Wf, bfb, Wh, bhb, Watt, batt, Wdp, Wup, out_xp, out_att);
    compute_store(3, n, yA + 6 + ly, xc, ry0, x0, fx, lds, B,
                  Wf, bfb, Wh, bhb, Watt, batt, Wdp, Wup, out_xp, out_att);
}

extern "C" void kernel_launch(void* const* d_in, const int* in_sizes, int n_in,
                              void* d_out, int out_size, void* d_ws, size_t ws_size,
                              hipStream_t stream) {
    const float* xf   = (const float*)d_in[0];
    const float* xh0  = (const float*)d_in[1];
    const float* xh1  = (const float*)d_in[2];
    const float* xp   = (const float*)d_in[3];
    const float* Wf   = (const float*)d_in[4];
    const float* bfb  = (const float*)d_in[5];
    const float* Wh   = (const float*)d_in[6];
    const float* bhb  = (const float*)d_in[7];
    const float* Watt = (const float*)d_in[8];
    const float* batt = (const float*)d_in[9];
    const float* Wdp  = (const float*)d_in[10];
    const float* Wup  = (const float*)d_in[11];

    int N = out_size / ((kP * kHD + kP) * kH * kH);
    if (N <= 0) N = 32;
    const int npix = N * kH * kH;

    float* out_xp  = (float*)d_out;
    float* out_att = out_xp + (size_t)N * kP * kHD * kH * kH;

    const int block = 256;
    const int grid = npix / 1024;          // 8 rows x 128 cols per block
    Part_Graph_51539607552364_kernel<<<grid, block, 0, stream>>>(
        xf, xh0, xh1, xp, Wf, bfb, Wh, bhb, Watt, batt, Wdp, Wup,
        out_xp, out_att);
}

// Round 8
// 298.934 us; speedup vs baseline: 1.6540x; 1.6540x over previous
//
#include <hip/hip_runtime.h>
#include <hip/hip_bf16.h>

constexpr int kHD  = 10;   // hidden dim
constexpr int kP   = 6;    // parts (3 per wave-group)
constexpr int kH   = 128;  // part-map H=W
constexpr int kHin = 64;   // coarse-map H=W
constexpr int kSeg = 70;   // 60 xh row-segments + 10 xf row-segments
constexpr int kExStride = 22;  // 20 xpv + 2 dpa per pixel per group

__device__ __forceinline__ float sigm(float v) {
    return 1.0f / (1.0f + __expf(-v));
}

// Block = 512 threads; 2 output rows x 128 cols (256 px) of one image.
// Waves 0-3: parts {0,1,2}; waves 4-7: parts {3,4,5} (same pixels).
// Halves per-thread live state, loads, FMAs, and weight streams; cross-group
// edges (2,3),(1,4) exchange xpv/dpa through LDS.
__global__ __launch_bounds__(512, 2)
void Part_Graph_51539607552364_kernel(
    const float* __restrict__ xf,  const float* __restrict__ xh0,
    const float* __restrict__ xh1, const float* __restrict__ xp,
    const float* __restrict__ Wf,  const float* __restrict__ bfb,
    const float* __restrict__ Wh,  const float* __restrict__ bhb,
    const float* __restrict__ Watt, const float* __restrict__ batt,
    const float* __restrict__ Wdp, const float* __restrict__ Wup,
    float* __restrict__ out_xp,
    float* __restrict__ out_att)
{
    __shared__ float stage[kSeg * kHin];            // 17920 B
    __shared__ float exbuf[2 * 256 * kExStride];    // 45056 B  (total 62976)

    const int bid = blockIdx.x;
    const int n   = bid >> 6;            // 64 blocks per image
    const int R   = bid & 63;            // row-pair index
    const int yA  = R * 2;

    const float scale = 63.0f / 127.0f;
    int ry0 = (int)((float)yA * scale);
    ry0 = ry0 > (kHin - 2) ? (kHin - 2) : ry0;

    // ---- cooperative staging of xh rows (3) x 2 maps x 10ch + xf row ----
    {
        const int wv = threadIdx.x >> 6;
        const int ln = threadIdx.x & 63;
        for (int s = wv; s < kSeg; s += 8) {
            const float* src;
            if (s < 60) {
                const int map = s / 30, rem = s % 30;
                const int ch = rem / 3, r3 = rem % 3;
                int row = ry0 + r3;
                row = row > (kHin - 1) ? (kHin - 1) : row;
                src = (map ? xh1 : xh0) +
                      ((size_t)(n * kHD + ch) * kHin + row) * kHin;
            } else {
                const int ch = s - 60;
                src = xf + ((size_t)(n * kHD + ch) * kHin + R) * kHin;
            }
            stage[s * kHin + ln] = src[ln];
        }
    }
    __syncthreads();

    const int g   = threadIdx.x >> 8;     // part-group 0/1
    const int t8  = threadIdx.x & 255;    // pixel slot 0..255
    const int ly  = t8 >> 7;              // row within pair
    const int xc  = t8 & (kH - 1);
    const int yc  = yA + ly;
    const int p0g = g * 3;                // first global part of my group

    // ---- bilinear coords ----
    const float py = (float)yc * scale;
    int y0 = (int)py; y0 = y0 > (kHin - 2) ? (kHin - 2) : y0;
    const float fy = py - (float)y0;
    const int d0 = y0 - ry0;              // 0/1
    const float pxf = (float)xc * scale;
    int x0 = (int)pxf; x0 = x0 > (kHin - 2) ? (kHin - 2) : x0;
    const float fx = pxf - (float)x0;
    const float w00 = (1.0f - fy) * (1.0f - fx);
    const float w01 = (1.0f - fy) * fx;
    const float w10 = fy * (1.0f - fx);
    const float w11 = fy * fx;

    // xh0 always; xh1 only for group 1 (parts 4,5)
    float xh0v[kHD], xh1v[kHD];
    #pragma unroll
    for (int c = 0; c < kHD; ++c) {
        const float* r0 = &stage[(c * 3 + d0) * kHin];
        xh0v[c] = r0[x0] * w00 + r0[x0 + 1] * w01 +
                  r0[kHin + x0] * w10 + r0[kHin + x0 + 1] * w11;
    }
    if (g) {
        #pragma unroll
        for (int c = 0; c < kHD; ++c) {
            const float* r1 = &stage[(30 + c * 3 + d0) * kHin];
            xh1v[c] = r1[x0] * w00 + r1[x0 + 1] * w01 +
                      r1[kHin + x0] * w10 + r1[kHin + x0 + 1] * w11;
        }
    } else {
        #pragma unroll
        for (int c = 0; c < kHD; ++c) xh1v[c] = 0.0f;
    }
    const int sx = xc >> 1;
    float xfv[kHD];
    #pragma unroll
    for (int c = 0; c < kHD; ++c) xfv[c] = stage[(60 + c) * kHin + sx];

    // ---- xp loads: my 3 parts only (30 coalesced dwords) ----
    float xpv[3][kHD];
    {
        const float* b = xp + (size_t)(n * kP * kHD) * (kH * kH) + yc * kH + xc;
        #pragma unroll
        for (int pl = 0; pl < 3; ++pl)
            #pragma unroll
            for (int c = 0; c < kHD; ++c)
                xpv[pl][c] = b[(size_t)((p0g + pl) * kHD + c) * (kH * kH)];
    }

    // ---- attentions for my parts ----
    float attf[3], atth[3], dpa[3];
    #pragma unroll
    for (int pl = 0; pl < 3; ++pl) {
        const int p = p0g + pl;
        float af = bfb[p];
        float ah = bhb[p];
        float ad = batt[p];
        #pragma unroll
        for (int c = 0; c < kHD; ++c) {
            const float xhc = (p < 4) ? xh0v[c] : xh1v[c];
            af += xfv[c]   * Wf[p * 2 * kHD + c];
            af += xpv[pl][c] * Wf[p * 2 * kHD + kHD + c];
            ah += xhc      * Wh[p * 2 * kHD + c];
            ah += xpv[pl][c] * Wh[p * 2 * kHD + kHD + c];
            ad += xpv[pl][c] * Watt[p * kHD + c];
        }
        attf[pl] = sigm(af);
        atth[pl] = sigm(ah);
        dpa[pl]  = sigm(ad);
    }

    // ---- exchange: g0 posts xpv[1],xpv[2],dpa[1],dpa[2]; g1 posts xpv[3],xpv[4],dpa[3],dpa[4]
    {
        float* ex = &exbuf[(g * 256 + t8) * kExStride];
        #pragma unroll
        for (int c = 0; c < kHD; ++c) {
            ex[c]       = xpv[1][c];   // g0: part1 | g1: part4? no: g1 pl1=4 -> slot10.. see below
            ex[kHD + c] = xpv[2][c];
        }
        ex[20] = dpa[1];
        ex[21] = dpa[2];
        // NOTE: for g1, pl: 0->part3,1->part4,2->part5. We need part3,part4:
        // overwrite slots with the correct parts for g1.
        if (g) {
            #pragma unroll
            for (int c = 0; c < kHD; ++c) {
                ex[c]       = xpv[0][c];  // part 3
                ex[kHD + c] = xpv[1][c];  // part 4
            }
            ex[20] = dpa[0];              // dpa[3]
            ex[21] = dpa[1];              // dpa[4]
        }
    }
    __syncthreads();

    // ---- edge messages into my parts ----
    float xpp[3][kHD];
    #pragma unroll
    for (int pl = 0; pl < 3; ++pl)
        #pragma unroll
        for (int c = 0; c < kHD; ++c) xpp[pl][c] = 0.0f;

    const float* exR = &exbuf[((1 - g) * 256 + t8) * kExStride];

    if (g == 0) {
        // local edges (0,1) e0 and (1,2) e1
        #pragma unroll
        for (int e = 0; e < 2; ++e) {   // e0: a=0,b=1 ; e1: a=1,b=2
            const int a = e, b = e + 1;
            const float sa = 2.0f - dpa[a];
            const float sb = 2.0f - dpa[b];
            #pragma unroll
            for (int d = 0; d < kHD; ++d) {
                const float* w = Wdp + (size_t)(e * kHD + d) * (2 * kHD);
                float t = 0.0f;
                #pragma unroll
                for (int c = 0; c < kHD; ++c) t += xpv[a][c] * w[c];
                #pragma unroll
                for (int c = 0; c < kHD; ++c) t += xpv[b][c] * w[kHD + c];
                t = fmaxf(t, 0.0f);
                xpp[b][d] += t * sa;
                xpp[a][d] += t * sb;
            }
        }
        // edge (2,3) e2: a=2 local, b=3 remote -> feeds my part 2
        {
            const float sb3 = 2.0f - exR[20];   // dpa[3]
            #pragma unroll
            for (int d = 0; d < kHD; ++d) {
                const float* w = Wdp + (size_t)(2 * kHD + d) * (2 * kHD);
                float t = 0.0f;
                #pragma unroll
                for (int c = 0; c < kHD; ++c) t += xpv[2][c] * w[c];
                #pragma unroll
                for (int c = 0; c < kHD; ++c) t += exR[c] * w[kHD + c];
                t = fmaxf(t, 0.0f);
                xpp[2][d] += t * sb3;
            }
        }
        // edge (1,4) e3: a=1 local, b=4 remote -> feeds my part 1
        {
            const float sb4 = 2.0f - exR[21];   // dpa[4]
            #pragma unroll
            for (int d = 0; d < kHD; ++d) {
                const float* w = Wdp + (size_t)(3 * kHD + d) * (2 * kHD);
                float t = 0.0f;
                #pragma unroll
                for (int c = 0; c < kHD; ++c) t += xpv[1][c] * w[c];
                #pragma unroll
                for (int c = 0; c < kHD; ++c) t += exR[kHD + c] * w[kHD + c];
                t = fmaxf(t, 0.0f);
                xpp[1][d] += t * sb4;
            }
        }
    } else {
        // edge (2,3) e2: a=2 remote, b=3=local pl0 -> feeds my part 3
        {
            const float sa2 = 2.0f - exR[21];   // dpa[2]
            #pragma unroll
            for (int d = 0; d < kHD; ++d) {
                const float* w = Wdp + (size_t)(2 * kHD + d) * (2 * kHD);
                float t = 0.0f;
                #pragma unroll
                for (int c = 0; c < kHD; ++c) t += exR[kHD + c] * w[c];   // xpv[2]
                #pragma unroll
                for (int c = 0; c < kHD; ++c) t += xpv[0][c] * w[kHD + c];
                t = fmaxf(t, 0.0f);
                xpp[0][d] += t * sa2;
            }
        }
        // edge (1,4) e3: a=1 remote, b=4=local pl1 -> feeds my part 4
        {
            const float sa1 = 2.0f - exR[20];   // dpa[1]
            #pragma unroll
            for (int d = 0; d < kHD; ++d) {
                const float* w = Wdp + (size_t)(3 * kHD + d) * (2 * kHD);
                float t = 0.0f;
                #pragma unroll
                for (int c = 0; c < kHD; ++c) t += exR[c] * w[c];         // xpv[1]
                #pragma unroll
                for (int c = 0; c < kHD; ++c) t += xpv[1][c] * w[kHD + c];
                t = fmaxf(t, 0.0f);
                xpp[1][d] += t * sa1;
            }
        }
        // local edge (4,5) e4: a=4=pl1, b=5=pl2
        {
            const float sa = 2.0f - dpa[1];
            const float sb = 2.0f - dpa[2];
            #pragma unroll
            for (int d = 0; d < kHD; ++d) {
                const float* w = Wdp + (size_t)(4 * kHD + d) * (2 * kHD);
                float t = 0.0f;
                #pragma unroll
                for (int c = 0; c < kHD; ++c) t += xpv[1][c] * w[c];
                #pragma unroll
                for (int c = 0; c < kHD; ++c) t += xpv[2][c] * w[kHD + c];
                t = fmaxf(t, 0.0f);
                xpp[2][d] += t * sa;
                xpp[1][d] += t * sb;
            }
        }
    }

    // ---- update + stores for my parts ----
    const size_t pixoff = (size_t)yc * kH + xc;
    #pragma unroll
    for (int pl = 0; pl < 3; ++pl) {
        const int p = p0g + pl;
        #pragma unroll
        for (int d = 0; d < kHD; ++d) {
            const float* w = Wup + (size_t)(p * kHD + d) * (4 * kHD);
            float a1 = 0.0f, a2 = 0.0f, a3 = 0.0f, a4 = 0.0f;
            #pragma unroll
            for (int c = 0; c < kHD; ++c) {
                const float xhc = (p < 4) ? xh0v[c] : xh1v[c];
                a1 += xpv[pl][c] * w[c];
                a2 += xfv[c]     * w[kHD + c];
                a3 += xhc        * w[2 * kHD + c];
                a4 += xpp[pl][c] * w[3 * kHD + c];
            }
            float upd = a1 + attf[pl] * a2 + atth[pl] * a3 + a4;
            upd = fmaxf(upd, 0.0f);
            float o = xpv[pl][d] + upd;
            o = fmaxf(o, 0.0f);
            out_xp[(size_t)(n * kP * kHD + p * kHD + d) * (kH * kH) + pixoff] = o;
        }
        const float ap = (attf[pl] + atth[pl] + dpa[pl]) * (1.0f / 3.0f);
        out_att[(size_t)(n * kP + p) * (kH * kH) + pixoff] = ap;
    }
}

extern "C" void kernel_launch(void* const* d_in, const int* in_sizes, int n_in,
                              void* d_out, int out_size, void* d_ws, size_t ws_size,
                              hipStream_t stream) {
    const float* xf   = (const float*)d_in[0];
    const float* xh0  = (const float*)d_in[1];
    const float* xh1  = (const float*)d_in[2];
    const float* xp   = (const float*)d_in[3];
    const float* Wf   = (const float*)d_in[4];
    const float* bfb  = (const float*)d_in[5];
    const float* Wh   = (const float*)d_in[6];
    const float* bhb  = (const float*)d_in[7];
    const float* Watt = (const float*)d_in[8];
    const float* batt = (const float*)d_in[9];
    const float* Wdp  = (const float*)d_in[10];
    const float* Wup  = (const float*)d_in[11];

    int N = out_size / ((kP * kHD + kP) * kH * kH);
    if (N <= 0) N = 32;
    const int npix = N * kH * kH;

    float* out_xp  = (float*)d_out;
    float* out_att = out_xp + (size_t)N * kP * kHD * kH * kH;

    const int block = 512;                // 8 waves: 2 part-groups x 256 px
    const int grid = npix / 256;          // 256 px per block
    Part_Graph_51539607552364_kernel<<<grid, block, 0, stream>>>(
        xf, xh0, xh1, xp, Wf, bfb, Wh, bhb, Watt, batt, Wdp, Wup,
        out_xp, out_att);
}